// Round 6
// baseline (1104.016 us; speedup 1.0000x reference)
//
#include <hip/hip_runtime.h>
#include <math.h>

// Native clang vector type (works with __builtin_nontemporal_*)
typedef float f4 __attribute__((ext_vector_type(4)));

// Problem constants
constexpr int Bn   = 32;
constexpr int Cn   = 256;
constexpr int Kn   = 4;
constexpr int HIDn = 32;
constexpr int HWn  = 56 * 56;        // 3136
constexpr int HW4n = HWn / 4;        // 784 f4 per plane
constexpr int CK1  = Cn * (Kn + 1);  // 1280

// Chunked pipeline: CB batches per chunk. Working set per chunk =
// CB*(K+1)*C*HW*4B = 64.2 MB; two chunks in flight = 128 MB << 256 MB L3,
// so the apply pass re-reads the previous chunk from L3, not HBM.
constexpr int CB          = 4;
constexpr int NCHUNK      = Bn / CB;            // 8
constexpr int POOL_ROWS   = CB * (Kn + 1) * Cn; // 5120 rows (one wave each)
constexpr int POOL_BLOCKS = POOL_ROWS / 4;      // 1280 (4 waves/block)
constexpr int APPLY_BLOCKS= CB * Cn;            // 1024 (one plane/block)

// ---------------------------------------------------------------------------
// init: zero the per-chunk pool-completion counters (graph replays reuse ws).
// ---------------------------------------------------------------------------
__global__ void init_kernel(int* __restrict__ ctr) {
    if (threadIdx.x < NCHUNK) ctr[threadIdx.x] = 0;
}

// ---------------------------------------------------------------------------
// PA kernel: [pool blocks for chunk pool_chunk] ++ [apply blocks for chunk
// apply_chunk]. Either part can be absent (-1). Pool part: wave-per-row
// cached loads (allocate in L3), then the LAST pool block (atomic counter)
// computes the MLP+gates for this chunk's CB batches. Apply part: uses gates
// of apply_chunk (finalized in the PREVIOUS kernel -> visible via kernel
// boundary), NT loads (L3 hits, dead after) + NT stores.
// ---------------------------------------------------------------------------
__global__ __launch_bounds__(256) void pa_kernel(
    const float* __restrict__ y, const float* __restrict__ x,
    const float* __restrict__ W1, const float* __restrict__ gamma,
    const float* __restrict__ beta, const float* __restrict__ W2,
    const float* __restrict__ bias2,
    float* __restrict__ w_in, float* __restrict__ gates,
    int* __restrict__ ctr, int pool_chunk, int apply_chunk)
{
    const int npool = (pool_chunk >= 0) ? POOL_BLOCKS : 0;

    if ((int)blockIdx.x < npool) {
        // ------------------------------ pool ------------------------------
        const int g    = pool_chunk;
        const int row  = blockIdx.x * 4 + (threadIdx.x >> 6);
        const int lane = threadIdx.x & 63;

        int b, k, c;
        const float* src;
        if (row < CB * Kn * Cn) {            // x rows: lb(2) | br(2) | c(8)
            int lb = row >> 10;
            int br = (row >> 8) & 3;
            c = row & 255;
            b = g * CB + lb;
            k = br + 1;
            src = x + ((size_t)(br * Bn + b) * Cn + c) * HWn;
        } else {                              // y rows
            int r2 = row - CB * Kn * Cn;
            int lb = r2 >> 8;
            c = r2 & 255;
            b = g * CB + lb;
            k = 0;
            src = y + (size_t)(b * Cn + c) * HWn;
        }

        const f4* s4 = reinterpret_cast<const f4*>(src);
        float s = 0.f;
        for (int i = lane; i < HW4n; i += 64) {
            f4 v = s4[i];                     // cached: allocate in L3
            s += (v.x + v.y) + (v.z + v.w);
        }
        #pragma unroll
        for (int off = 32; off > 0; off >>= 1) s += __shfl_xor(s, off, 64);
        if (lane == 0) w_in[b * CK1 + k * Cn + c] = s * (1.0f / (float)HWn);

        // last pool block of this chunk computes the MLP + gates
        __shared__ int is_last;
        __syncthreads();
        if (threadIdx.x == 0) {
            __threadfence();
            int r = atomicAdd(&ctr[g], 1);
            is_last = (r == POOL_BLOCKS - 1) ? 1 : 0;
        }
        __syncthreads();
        if (is_last) {
            __threadfence();   // acquire: see all pool blocks' w_in writes
            __shared__ float s_in[CK1];
            __shared__ float s_h[HIDn];
            for (int lb = 0; lb < CB; ++lb) {
                const int bb = g * CB + lb;
                for (int i = threadIdx.x; i < CK1; i += 256)
                    s_in[i] = w_in[bb * CK1 + i];
                __syncthreads();
                {   // h = relu(w_in @ W1^T * gamma + beta): 8 threads/output
                    int j   = threadIdx.x >> 3;
                    int sub = threadIdx.x & 7;
                    const float* w1row = W1 + j * CK1;
                    float p = 0.f;
                    for (int i = sub; i < CK1; i += 8) p += s_in[i] * w1row[i];
                    p += __shfl_xor(p, 1);
                    p += __shfl_xor(p, 2);
                    p += __shfl_xor(p, 4);
                    if (sub == 0) {
                        float hv = p * gamma[j] + beta[j];
                        s_h[j] = hv > 0.f ? hv : 0.f;
                    }
                }
                __syncthreads();
                // each thread owns one channel: all 5 outputs + gates
                const int c2 = threadIdx.x;   // 0..255 == Cn
                float wv[5];
                #pragma unroll
                for (int k2 = 0; k2 < 5; ++k2) {
                    const float* w2row = W2 + (size_t)(k2 * Cn + c2) * HIDn;
                    float acc = bias2[k2 * Cn + c2];
                    #pragma unroll
                    for (int i = 0; i < HIDn; ++i) acc += s_h[i] * w2row[i];
                    wv[k2] = acc;
                }
                float g0 = 1.f / (1.f + expf(-wv[0]));
                float m  = fmaxf(fmaxf(wv[1], wv[2]), fmaxf(wv[3], wv[4]));
                float e1 = expf(wv[1] - m), e2 = expf(wv[2] - m);
                float e3 = expf(wv[3] - m), e4 = expf(wv[4] - m);
                float inv = 1.f / (e1 + e2 + e3 + e4);
                float* gg = gates + (size_t)bb * (5 * Cn);
                gg[c2]          = g0;
                gg[Cn + c2]     = e1 * inv;
                gg[2 * Cn + c2] = e2 * inv;
                gg[3 * Cn + c2] = e3 * inv;
                gg[4 * Cn + c2] = e4 * inv;
                __syncthreads();
            }
        }
    } else {
        // ------------------------------ apply -----------------------------
        const int ab = blockIdx.x - npool;    // 0..APPLY_BLOCKS-1
        const int g  = apply_chunk;
        const int lb = ab >> 8;
        const int c  = ab & 255;
        const int b  = g * CB + lb;

        const float* gg = gates + (size_t)b * (5 * Cn);
        const float g0 = gg[c];
        const float g1 = gg[Cn + c];
        const float g2 = gg[2 * Cn + c];
        const float g3 = gg[3 * Cn + c];
        const float g4 = gg[4 * Cn + c];

        const size_t plane = (size_t)(b * Cn + c) * HWn;
        const size_t xstep = (size_t)Bn * Cn * HWn;
        const f4* y4  = reinterpret_cast<const f4*>(y + plane);
        const f4* x14 = reinterpret_cast<const f4*>(x + plane);
        const f4* x24 = reinterpret_cast<const f4*>(x + plane + xstep);
        const f4* x34 = reinterpret_cast<const f4*>(x + plane + 2 * xstep);
        const f4* x44 = reinterpret_cast<const f4*>(x + plane + 3 * xstep);
        f4* o4 = reinterpret_cast<f4*>((float*)0 + 0) ;  // placeholder removed below
        (void)o4;
        f4* out4 = reinterpret_cast<f4*>(const_cast<float*>(y)) ; // not used
        (void)out4;
        // real out pointer passed via w_in? -- no: see extern out param below
        // (out pointer is passed as 'gates+...'? no) -- we pass out separately:
        // NOTE: out is smuggled through the 'ctr' extra arg? No -- kept clean:
        // out is the last kernel parameter (see signature change below).
        // -- this branch rewritten in out-bearing version --
    }
}

// The apply part needs the out pointer; cleanest is a dedicated signature.
// Full kernel used by the launcher (pool+apply with out):
__global__ __launch_bounds__(256) void pa_kernel_full(
    const float* __restrict__ y, const float* __restrict__ x,
    const float* __restrict__ W1, const float* __restrict__ gamma,
    const float* __restrict__ beta, const float* __restrict__ W2,
    const float* __restrict__ bias2,
    float* __restrict__ w_in, float* __restrict__ gates,
    int* __restrict__ ctr, float* __restrict__ out,
    int pool_chunk, int apply_chunk)
{
    const int npool = (pool_chunk >= 0) ? POOL_BLOCKS : 0;

    if ((int)blockIdx.x < npool) {
        const int g    = pool_chunk;
        const int row  = blockIdx.x * 4 + (threadIdx.x >> 6);
        const int lane = threadIdx.x & 63;

        int b, k, c;
        const float* src;
        if (row < CB * Kn * Cn) {
            int lb = row >> 10;
            int br = (row >> 8) & 3;
            c = row & 255;
            b = g * CB + lb;
            k = br + 1;
            src = x + ((size_t)(br * Bn + b) * Cn + c) * HWn;
        } else {
            int r2 = row - CB * Kn * Cn;
            int lb = r2 >> 8;
            c = r2 & 255;
            b = g * CB + lb;
            k = 0;
            src = y + (size_t)(b * Cn + c) * HWn;
        }

        const f4* s4 = reinterpret_cast<const f4*>(src);
        float s = 0.f;
        for (int i = lane; i < HW4n; i += 64) {
            f4 v = s4[i];
            s += (v.x + v.y) + (v.z + v.w);
        }
        #pragma unroll
        for (int off = 32; off > 0; off >>= 1) s += __shfl_xor(s, off, 64);
        if (lane == 0) w_in[b * CK1 + k * Cn + c] = s * (1.0f / (float)HWn);

        __shared__ int is_last;
        __syncthreads();
        if (threadIdx.x == 0) {
            __threadfence();
            int r = atomicAdd(&ctr[g], 1);
            is_last = (r == POOL_BLOCKS - 1) ? 1 : 0;
        }
        __syncthreads();
        if (is_last) {
            __threadfence();
            __shared__ float s_in[CK1];
            __shared__ float s_h[HIDn];
            for (int lb = 0; lb < CB; ++lb) {
                const int bb = g * CB + lb;
                for (int i = threadIdx.x; i < CK1; i += 256)
                    s_in[i] = w_in[bb * CK1 + i];
                __syncthreads();
                {
                    int j   = threadIdx.x >> 3;
                    int sub = threadIdx.x & 7;
                    const float* w1row = W1 + j * CK1;
                    float p = 0.f;
                    for (int i = sub; i < CK1; i += 8) p += s_in[i] * w1row[i];
                    p += __shfl_xor(p, 1);
                    p += __shfl_xor(p, 2);
                    p += __shfl_xor(p, 4);
                    if (sub == 0) {
                        float hv = p * gamma[j] + beta[j];
                        s_h[j] = hv > 0.f ? hv : 0.f;
                    }
                }
                __syncthreads();
                const int c2 = threadIdx.x;
                float wv[5];
                #pragma unroll
                for (int k2 = 0; k2 < 5; ++k2) {
                    const float* w2row = W2 + (size_t)(k2 * Cn + c2) * HIDn;
                    float acc = bias2[k2 * Cn + c2];
                    #pragma unroll
                    for (int i = 0; i < HIDn; ++i) acc += s_h[i] * w2row[i];
                    wv[k2] = acc;
                }
                float g0 = 1.f / (1.f + expf(-wv[0]));
                float m  = fmaxf(fmaxf(wv[1], wv[2]), fmaxf(wv[3], wv[4]));
                float e1 = expf(wv[1] - m), e2 = expf(wv[2] - m);
                float e3 = expf(wv[3] - m), e4 = expf(wv[4] - m);
                float inv = 1.f / (e1 + e2 + e3 + e4);
                float* gg = gates + (size_t)bb * (5 * Cn);
                gg[c2]          = g0;
                gg[Cn + c2]     = e1 * inv;
                gg[2 * Cn + c2] = e2 * inv;
                gg[3 * Cn + c2] = e3 * inv;
                gg[4 * Cn + c2] = e4 * inv;
                __syncthreads();
            }
        }
    } else {
        const int ab = blockIdx.x - npool;
        const int g  = apply_chunk;
        const int lb = ab >> 8;
        const int c  = ab & 255;
        const int b  = g * CB + lb;

        const float* gg = gates + (size_t)b * (5 * Cn);
        const float g0 = gg[c];
        const float g1 = gg[Cn + c];
        const float g2 = gg[2 * Cn + c];
        const float g3 = gg[3 * Cn + c];
        const float g4 = gg[4 * Cn + c];

        const size_t plane = (size_t)(b * Cn + c) * HWn;
        const size_t xstep = (size_t)Bn * Cn * HWn;
        const f4* y4  = reinterpret_cast<const f4*>(y + plane);
        const f4* x14 = reinterpret_cast<const f4*>(x + plane);
        const f4* x24 = reinterpret_cast<const f4*>(x + plane + xstep);
        const f4* x34 = reinterpret_cast<const f4*>(x + plane + 2 * xstep);
        const f4* x44 = reinterpret_cast<const f4*>(x + plane + 3 * xstep);
        f4* o4 = reinterpret_cast<f4*>(out + plane);

        for (int i = threadIdx.x; i < HW4n; i += 256) {
            f4 vy = __builtin_nontemporal_load(y4 + i);   // L3 hit, dead after
            f4 v1 = __builtin_nontemporal_load(x14 + i);
            f4 v2 = __builtin_nontemporal_load(x24 + i);
            f4 v3 = __builtin_nontemporal_load(x34 + i);
            f4 v4 = __builtin_nontemporal_load(x44 + i);
            f4 r;
            r.x = vy.x * g0 + v1.x * g1 + v2.x * g2 + v3.x * g3 + v4.x * g4;
            r.y = vy.y * g0 + v1.y * g1 + v2.y * g2 + v3.y * g3 + v4.y * g4;
            r.z = vy.z * g0 + v1.z * g1 + v2.z * g2 + v3.z * g3 + v4.z * g4;
            r.w = vy.w * g0 + v1.w * g1 + v2.w * g2 + v3.w * g3 + v4.w * g4;
            __builtin_nontemporal_store(r, o4 + i);
        }
    }
}

extern "C" void kernel_launch(void* const* d_in, const int* in_sizes, int n_in,
                              void* d_out, int out_size, void* d_ws, size_t ws_size,
                              hipStream_t stream) {
    const float* y     = (const float*)d_in[0];
    const float* x     = (const float*)d_in[1];
    const float* W1    = (const float*)d_in[2];
    const float* gamma = (const float*)d_in[3];
    const float* beta  = (const float*)d_in[4];
    const float* W2    = (const float*)d_in[5];
    const float* b2    = (const float*)d_in[6];
    float* out = (float*)d_out;

    float* w_in  = (float*)d_ws;                        // [B][CK1]
    float* gates = w_in + (size_t)Bn * CK1;             // [B][5*C]
    int*   ctr   = (int*)(gates + (size_t)Bn * 5 * Cn); // [NCHUNK]

    init_kernel<<<1, 64, 0, stream>>>(ctr);

    // PA(0): pool chunk 0 only
    pa_kernel_full<<<POOL_BLOCKS, 256, 0, stream>>>(
        y, x, W1, gamma, beta, W2, b2, w_in, gates, ctr, out, 0, -1);
    // PA(1..NCHUNK-1): pool chunk g + apply chunk g-1
    for (int g = 1; g < NCHUNK; ++g) {
        pa_kernel_full<<<POOL_BLOCKS + APPLY_BLOCKS, 256, 0, stream>>>(
            y, x, W1, gamma, beta, W2, b2, w_in, gates, ctr, out, g, g - 1);
    }
    // PA(NCHUNK): apply chunk NCHUNK-1 only
    pa_kernel_full<<<APPLY_BLOCKS, 256, 0, stream>>>(
        y, x, W1, gamma, beta, W2, b2, w_in, gates, ctr, out, -1, NCHUNK - 1);
}

// Round 7
// 365.187 us; speedup vs baseline: 3.0232x; 3.0232x over previous
//
#include <hip/hip_runtime.h>
#include <math.h>

// Native clang vector type (works with __builtin_nontemporal_*)
typedef float f4 __attribute__((ext_vector_type(4)));

// Problem constants
constexpr int Bn   = 32;
constexpr int Cn   = 256;
constexpr int Kn   = 4;
constexpr int HIDn = 32;
constexpr int HWn  = 56 * 56;        // 3136
constexpr int HW4n = HWn / 4;        // 784 f4 per plane
constexpr int CK1  = Cn * (Kn + 1);  // 1280

// Fence-free chunked pipeline: CB batches per chunk; kernel g runs
//   [mlp blocks, chunk g-1] [pool blocks, chunk g] [apply blocks, chunk g-2]
// Every producer->consumer edge crosses a kernel boundary (stream order), so
// no atomics / fences / spinning. 3 chunks in flight = 192 MB < 256 MB MALL,
// so apply re-reads its chunk from the Infinity Cache, not HBM.
constexpr int CB          = 4;
constexpr int NCHUNK      = Bn / CB;            // 8
constexpr int POOL_ROWS   = CB * (Kn + 1) * Cn; // 5120 rows (one wave each)
constexpr int POOL_BLOCKS = POOL_ROWS / 4;      // 1280 (4 waves/block)
constexpr int APPLY_BLOCKS= CB * Cn;            // 1024 (one plane per block)

__global__ __launch_bounds__(256) void pa_kernel(
    const float* __restrict__ y, const float* __restrict__ x,
    const float* __restrict__ W1, const float* __restrict__ gamma,
    const float* __restrict__ beta, const float* __restrict__ W2,
    const float* __restrict__ bias2,
    float* __restrict__ w_in, float* __restrict__ gates,
    float* __restrict__ out,
    int pool_chunk, int mlp_chunk, int apply_chunk)
{
    const int nmlp  = (mlp_chunk  >= 0) ? CB : 0;
    const int npool = (pool_chunk >= 0) ? POOL_BLOCKS : 0;
    const int bid   = blockIdx.x;

    if (bid < nmlp) {
        // --------------------------- MLP (chunk g-1) ---------------------------
        // One block per batch; reads w_in written by the PREVIOUS kernel's pool.
        const int b = mlp_chunk * CB + bid;
        __shared__ float s_in[CK1];
        __shared__ float s_h[HIDn];
        for (int i = threadIdx.x; i < CK1; i += 256) s_in[i] = w_in[b * CK1 + i];
        __syncthreads();
        {   // h = relu((w_in @ W1^T) * gamma + beta): 8 threads per output j
            int j   = threadIdx.x >> 3;
            int sub = threadIdx.x & 7;
            const float* w1row = W1 + j * CK1;
            float p = 0.f;
            for (int i = sub; i < CK1; i += 8) p += s_in[i] * w1row[i];
            p += __shfl_xor(p, 1);
            p += __shfl_xor(p, 2);
            p += __shfl_xor(p, 4);
            if (sub == 0) {
                float hv = p * gamma[j] + beta[j];
                s_h[j] = hv > 0.f ? hv : 0.f;
            }
        }
        __syncthreads();
        // each thread owns one channel: all 5 outputs -> sigmoid / softmax
        const int c = threadIdx.x;   // 0..255 == Cn
        float wv[5];
        #pragma unroll
        for (int k2 = 0; k2 < 5; ++k2) {
            const float* w2row = W2 + (size_t)(k2 * Cn + c) * HIDn;
            float acc = bias2[k2 * Cn + c];
            #pragma unroll
            for (int i = 0; i < HIDn; ++i) acc += s_h[i] * w2row[i];
            wv[k2] = acc;
        }
        float g0 = 1.f / (1.f + expf(-wv[0]));
        float m  = fmaxf(fmaxf(wv[1], wv[2]), fmaxf(wv[3], wv[4]));
        float e1 = expf(wv[1] - m), e2 = expf(wv[2] - m);
        float e3 = expf(wv[3] - m), e4 = expf(wv[4] - m);
        float inv = 1.f / (e1 + e2 + e3 + e4);
        float* gg = gates + (size_t)b * (5 * Cn);
        gg[c]          = g0;
        gg[Cn + c]     = e1 * inv;
        gg[2 * Cn + c] = e2 * inv;
        gg[3 * Cn + c] = e3 * inv;
        gg[4 * Cn + c] = e4 * inv;
    } else if (bid < nmlp + npool) {
        // --------------------------- pool (chunk g) ----------------------------
        const int g    = pool_chunk;
        const int row  = (bid - nmlp) * 4 + (threadIdx.x >> 6);
        const int lane = threadIdx.x & 63;

        int b, k, c;
        const float* src;
        if (row < CB * Kn * Cn) {            // x rows: lb(2) | br(2) | c(8)
            int lb = row >> 10;
            int br = (row >> 8) & 3;
            c = row & 255;
            b = g * CB + lb;
            k = br + 1;
            src = x + ((size_t)(br * Bn + b) * Cn + c) * HWn;
        } else {                              // y rows
            int r2 = row - CB * Kn * Cn;
            int lb = r2 >> 8;
            c = r2 & 255;
            b = g * CB + lb;
            k = 0;
            src = y + (size_t)(b * Cn + c) * HWn;
        }

        const f4* s4 = reinterpret_cast<const f4*>(src);
        float s = 0.f;
        for (int i = lane; i < HW4n; i += 64) {
            f4 v = s4[i];                     // cached: allocate in L3
            s += (v.x + v.y) + (v.z + v.w);
        }
        #pragma unroll
        for (int off = 32; off > 0; off >>= 1) s += __shfl_xor(s, off, 64);
        if (lane == 0) w_in[b * CK1 + k * Cn + c] = s * (1.0f / (float)HWn);
    } else {
        // --------------------------- apply (chunk g-2) -------------------------
        const int ab = bid - nmlp - npool;    // 0..APPLY_BLOCKS-1
        const int lb = ab >> 8;
        const int c  = ab & 255;
        const int b  = apply_chunk * CB + lb;

        const float* gg = gates + (size_t)b * (5 * Cn);
        const float g0 = gg[c];
        const float g1 = gg[Cn + c];
        const float g2 = gg[2 * Cn + c];
        const float g3 = gg[3 * Cn + c];
        const float g4 = gg[4 * Cn + c];

        const size_t plane = (size_t)(b * Cn + c) * HWn;
        const size_t xstep = (size_t)Bn * Cn * HWn;
        const f4* y4  = reinterpret_cast<const f4*>(y + plane);
        const f4* x14 = reinterpret_cast<const f4*>(x + plane);
        const f4* x24 = reinterpret_cast<const f4*>(x + plane + xstep);
        const f4* x34 = reinterpret_cast<const f4*>(x + plane + 2 * xstep);
        const f4* x44 = reinterpret_cast<const f4*>(x + plane + 3 * xstep);
        f4* o4 = reinterpret_cast<f4*>(out + plane);

        for (int i = threadIdx.x; i < HW4n; i += 256) {
            f4 vy = __builtin_nontemporal_load(y4 + i);   // L3 hit, dead after
            f4 v1 = __builtin_nontemporal_load(x14 + i);
            f4 v2 = __builtin_nontemporal_load(x24 + i);
            f4 v3 = __builtin_nontemporal_load(x34 + i);
            f4 v4 = __builtin_nontemporal_load(x44 + i);
            f4 r;
            r.x = vy.x * g0 + v1.x * g1 + v2.x * g2 + v3.x * g3 + v4.x * g4;
            r.y = vy.y * g0 + v1.y * g1 + v2.y * g2 + v3.y * g3 + v4.y * g4;
            r.z = vy.z * g0 + v1.z * g1 + v2.z * g2 + v3.z * g3 + v4.z * g4;
            r.w = vy.w * g0 + v1.w * g1 + v2.w * g2 + v3.w * g3 + v4.w * g4;
            __builtin_nontemporal_store(r, o4 + i);
        }
    }
}

extern "C" void kernel_launch(void* const* d_in, const int* in_sizes, int n_in,
                              void* d_out, int out_size, void* d_ws, size_t ws_size,
                              hipStream_t stream) {
    const float* y     = (const float*)d_in[0];
    const float* x     = (const float*)d_in[1];
    const float* W1    = (const float*)d_in[2];
    const float* gamma = (const float*)d_in[3];
    const float* beta  = (const float*)d_in[4];
    const float* W2    = (const float*)d_in[5];
    const float* b2    = (const float*)d_in[6];
    float* out = (float*)d_out;

    float* w_in  = (float*)d_ws;                        // [B][CK1]
    float* gates = w_in + (size_t)Bn * CK1;             // [B][5*C]

    // kernel step s: pool chunk s, mlp chunk s-1, apply chunk s-2
    for (int s = 0; s < NCHUNK + 2; ++s) {
        int pc = (s < NCHUNK) ? s : -1;
        int mc = (s - 1 >= 0 && s - 1 < NCHUNK) ? (s - 1) : -1;
        int ac = (s - 2 >= 0 && s - 2 < NCHUNK) ? (s - 2) : -1;
        int nblocks = (mc >= 0 ? CB : 0) + (pc >= 0 ? POOL_BLOCKS : 0)
                    + (ac >= 0 ? APPLY_BLOCKS : 0);
        pa_kernel<<<nblocks, 256, 0, stream>>>(
            y, x, W1, gamma, beta, W2, b2, w_in, gates, out, pc, mc, ac);
    }
}

// Round 8
// 192.417 us; speedup vs baseline: 5.7376x; 1.8979x over previous
//
#include <hip/hip_runtime.h>
#include <math.h>

// Native clang vector type (works with __builtin_nontemporal_*)
typedef float f4 __attribute__((ext_vector_type(4)));

// Problem constants
constexpr int Bn   = 32;
constexpr int Cn   = 256;
constexpr int Kn   = 4;
constexpr int HIDn = 32;
constexpr int HWn  = 56 * 56;        // 3136
constexpr int HW4n = HWn / 4;        // 784 f4 per plane
constexpr int CK1  = Cn * (Kn + 1);  // 1280
constexpr int ROWS = (Kn + 1) * Bn * Cn;  // 40960 pool rows

// Best-measured structure (R4, 192.7us): 3 streaming kernels, wave-per-row
// pool, NT on x branches 1-3 + out, cached y + x-branch-0. Chunked pipelines
// and ordering tricks all measured worse (R5: 195, R6: 1104, R7: 365).

// ---------------------------------------------------------------------------
// Kernel 1: global average pool. ONE WAVE per (k,b,c) row.
// y (k=0) and x-branch-0 (k=1) cached; x branches 1-3 nontemporal.
// ---------------------------------------------------------------------------
__global__ __launch_bounds__(256) void pool_kernel(const float* __restrict__ y,
                                                   const float* __restrict__ x,
                                                   float* __restrict__ w_in) {
    int row  = blockIdx.x * 4 + (threadIdx.x >> 6);   // global wave id = row
    int lane = threadIdx.x & 63;
    if (row >= ROWS) return;

    int c  = row % Cn;
    int kb = row / Cn;
    int b  = kb % Bn;
    int k  = kb / Bn;

    float s = 0.f;
    if (k <= 1) {  // cached tier: y or x-branch-0
        const float* src = (k == 0)
            ? (y + (size_t)(b * Cn + c) * HWn)
            : (x + (size_t)(b * Cn + c) * HWn);
        const f4* s4 = reinterpret_cast<const f4*>(src);
        for (int i = lane; i < HW4n; i += 64) {
            f4 v = s4[i];
            s += (v.x + v.y) + (v.z + v.w);
        }
    } else {       // streaming tier: x branches 1-3, nontemporal
        const f4* s4 = reinterpret_cast<const f4*>(
            x + ((size_t)((k - 1) * Bn + b) * Cn + c) * HWn);
        for (int i = lane; i < HW4n; i += 64) {
            f4 v = __builtin_nontemporal_load(s4 + i);
            s += (v.x + v.y) + (v.z + v.w);
        }
    }

    // 64-lane butterfly reduce
    #pragma unroll
    for (int off = 32; off > 0; off >>= 1) s += __shfl_xor(s, off, 64);

    if (lane == 0) w_in[b * CK1 + k * Cn + c] = s * (1.0f / (float)HWn);
}

// ---------------------------------------------------------------------------
// Kernel 2: tiny MLP + gates. One block per batch (32 blocks x 256 threads).
// ---------------------------------------------------------------------------
__global__ __launch_bounds__(256) void mlp_kernel(const float* __restrict__ w_in,
                                                  const float* __restrict__ W1,
                                                  const float* __restrict__ gamma,
                                                  const float* __restrict__ beta,
                                                  const float* __restrict__ W2,
                                                  const float* __restrict__ b2,
                                                  float* __restrict__ gates) {
    int b = blockIdx.x;
    __shared__ float s_in[CK1];
    __shared__ float s_h[HIDn];
    __shared__ float s_w[CK1];

    for (int i = threadIdx.x; i < CK1; i += 256) s_in[i] = w_in[b * CK1 + i];
    __syncthreads();

    // h: 8 threads per output j (32 j's x 8 = 256 threads)
    {
        int j   = threadIdx.x >> 3;  // 0..31
        int sub = threadIdx.x & 7;
        const float* w1row = W1 + j * CK1;
        float p = 0.f;
        for (int i = sub; i < CK1; i += 8) p += s_in[i] * w1row[i];
        p += __shfl_xor(p, 1);
        p += __shfl_xor(p, 2);
        p += __shfl_xor(p, 4);
        if (sub == 0) {
            float hv = p * gamma[j] + beta[j];
            s_h[j] = hv > 0.f ? hv : 0.f;
        }
    }
    __syncthreads();

    // w = h @ W2^T + b2
    for (int o = threadIdx.x; o < CK1; o += 256) {
        const float* w2row = W2 + o * HIDn;
        float acc = b2[o];
        #pragma unroll
        for (int i = 0; i < HIDn; ++i) acc += s_h[i] * w2row[i];
        s_w[o] = acc;
    }
    __syncthreads();

    // gates (one thread per channel c)
    int c = threadIdx.x;  // 256 threads == C
    float g0 = 1.f / (1.f + expf(-s_w[c]));
    float s1 = s_w[Cn + c], s2 = s_w[2 * Cn + c], s3 = s_w[3 * Cn + c], s4 = s_w[4 * Cn + c];
    float m  = fmaxf(fmaxf(s1, s2), fmaxf(s3, s4));
    float e1 = expf(s1 - m), e2 = expf(s2 - m), e3 = expf(s3 - m), e4 = expf(s4 - m);
    float inv = 1.f / (e1 + e2 + e3 + e4);
    float* g = gates + (size_t)b * (5 * Cn);
    g[c]          = g0;
    g[Cn + c]     = e1 * inv;
    g[2 * Cn + c] = e2 * inv;
    g[3 * Cn + c] = e3 * inv;
    g[4 * Cn + c] = e4 * inv;
}

// ---------------------------------------------------------------------------
// Kernel 3: apply gates. One block per (b,c) plane, f4 fused weighted sum.
// y + x-branch-0 cached; x branches 1-3 NT; out store NT.
// ---------------------------------------------------------------------------
__global__ __launch_bounds__(256) void apply_kernel(const float* __restrict__ y,
                                                    const float* __restrict__ x,
                                                    const float* __restrict__ gates,
                                                    float* __restrict__ out) {
    int bid = blockIdx.x;     // b*C + c
    int c = bid % Cn;
    int b = bid / Cn;
    const float* g = gates + (size_t)b * (5 * Cn);
    float g0 = g[c];
    float g1 = g[Cn + c];
    float g2 = g[2 * Cn + c];
    float g3 = g[3 * Cn + c];
    float g4 = g[4 * Cn + c];

    size_t plane = (size_t)bid * HWn;
    size_t xstep = (size_t)Bn * Cn * HWn;
    const f4* y4  = reinterpret_cast<const f4*>(y + plane);
    const f4* x14 = reinterpret_cast<const f4*>(x + plane);
    const f4* x24 = reinterpret_cast<const f4*>(x + plane + xstep);
    const f4* x34 = reinterpret_cast<const f4*>(x + plane + 2 * xstep);
    const f4* x44 = reinterpret_cast<const f4*>(x + plane + 3 * xstep);
    f4* o4 = reinterpret_cast<f4*>(out + plane);

    for (int i = threadIdx.x; i < HW4n; i += 256) {
        f4 vy = y4[i];                                    // cached
        f4 v1 = x14[i];                                   // cached
        f4 v2 = __builtin_nontemporal_load(x24 + i);
        f4 v3 = __builtin_nontemporal_load(x34 + i);
        f4 v4 = __builtin_nontemporal_load(x44 + i);
        f4 r;
        r.x = vy.x * g0 + v1.x * g1 + v2.x * g2 + v3.x * g3 + v4.x * g4;
        r.y = vy.y * g0 + v1.y * g1 + v2.y * g2 + v3.y * g3 + v4.y * g4;
        r.z = vy.z * g0 + v1.z * g1 + v2.z * g2 + v3.z * g3 + v4.z * g4;
        r.w = vy.w * g0 + v1.w * g1 + v2.w * g2 + v3.w * g3 + v4.w * g4;
        __builtin_nontemporal_store(r, o4 + i);
    }
}

extern "C" void kernel_launch(void* const* d_in, const int* in_sizes, int n_in,
                              void* d_out, int out_size, void* d_ws, size_t ws_size,
                              hipStream_t stream) {
    const float* y     = (const float*)d_in[0];
    const float* x     = (const float*)d_in[1];
    const float* W1    = (const float*)d_in[2];
    const float* gamma = (const float*)d_in[3];
    const float* beta  = (const float*)d_in[4];
    const float* W2    = (const float*)d_in[5];
    const float* b2    = (const float*)d_in[6];
    float* out = (float*)d_out;

    float* w_in  = (float*)d_ws;                       // [B, CK1]
    float* gates = w_in + (size_t)Bn * CK1;            // [B, 5, C]

    pool_kernel<<<ROWS / 4, 256, 0, stream>>>(y, x, w_in);
    mlp_kernel<<<Bn, 256, 0, stream>>>(w_in, W1, gamma, beta, W2, b2, gates);
    apply_kernel<<<Bn * Cn, 256, 0, stream>>>(y, x, gates, out);
}